// Round 5
// baseline (487.199 us; speedup 1.0000x reference)
//
#include <hip/hip_runtime.h>

// Problem constants (from reference setup_inputs): B=2, L=10000, H=8, E=64, NE=160000
#define BB 2
#define HH 8
#define EE 64
#define ROW (HH * EE)        // 512 elements per (b, node) row
#define KVROW (2 * ROW)      // interleaved [k|v] row: 1024 bf16 = 2 KB
#define CHUNK 8

// ---------- fp32 -> bf16 (RNE) ----------
__device__ inline unsigned short f2bf(float f) {
  unsigned int u = __float_as_uint(f);
  u = (u + 0x7fffu + ((u >> 16) & 1u)) >> 16;
  return (unsigned short)u;
}

// convert k,v into interleaved bf16 layout kv[b*L+node] = [k(512) | v(512)];
// threads [0, NE) also histogram dst into counts.
__global__ __launch_bounds__(256) void convert_hist_kernel(
    const float* __restrict__ k, const float* __restrict__ v,
    unsigned short* __restrict__ kv,
    const int* __restrict__ dst, int* __restrict__ counts,
    int n4, int NE) {
  int i = blockIdx.x * blockDim.x + threadIdx.x;
  if (i < n4) {
    float4 kf = ((const float4*)k)[i];
    float4 vf = ((const float4*)v)[i];
    int row = i >> 7;          // 128 float4 per 512-elem row
    int p4 = i & 127;
    ushort4* kvrow = (ushort4*)(kv + (size_t)row * KVROW);
    kvrow[p4]       = make_ushort4(f2bf(kf.x), f2bf(kf.y), f2bf(kf.z), f2bf(kf.w));
    kvrow[128 + p4] = make_ushort4(f2bf(vf.x), f2bf(vf.y), f2bf(vf.z), f2bf(vf.w));
  }
  if (i < NE) {
    atomicAdd(&counts[dst[i]], 1);
  }
}

// single-block scan: counts -> offsets[0..L]; zero counts (reused as fill cursor)
__global__ __launch_bounds__(1024) void scan_kernel(
    const int* __restrict__ counts_in, int* __restrict__ counts_mut,
    int* __restrict__ offsets, int L) {
  __shared__ int sums[1024];
  int tid = threadIdx.x;
  int chunk = (L + 1023) / 1024;
  int beg = tid * chunk;
  int end = min(beg + chunk, L);
  int s = 0;
  for (int i = beg; i < end; ++i) s += counts_in[i];
  sums[tid] = s;
  __syncthreads();
  for (int off = 1; off < 1024; off <<= 1) {
    int val = 0;
    if (tid >= off) val = sums[tid - off];
    __syncthreads();
    if (tid >= off) sums[tid] += val;
    __syncthreads();
  }
  int run = (tid > 0) ? sums[tid - 1] : 0;
  for (int i = beg; i < end; ++i) {
    offsets[i] = run;
    run += counts_in[i];
    counts_mut[i] = 0;
  }
  if (tid == 1023) offsets[L] = run;
}

__global__ __launch_bounds__(256) void fill_csr_kernel(
    const int* __restrict__ dst, const int* __restrict__ src,
    const int* __restrict__ offsets, int* __restrict__ cursor,
    int* __restrict__ csr_src, int NE) {
  int e = blockIdx.x * blockDim.x + threadIdx.x;
  if (e >= NE) return;
  int d = dst[e];
  int pos = atomicAdd(&cursor[d], 1);
  csr_src[offsets[d] + pos] = src[e];
}

// ---------- fused flash-style kernel: persistent waves, ticket per (dst, b) ----------
__device__ inline void bf8_unpack(uint4 u, float* f) {
  f[0] = __uint_as_float(u.x << 16);
  f[1] = __uint_as_float(u.x & 0xffff0000u);
  f[2] = __uint_as_float(u.y << 16);
  f[3] = __uint_as_float(u.y & 0xffff0000u);
  f[4] = __uint_as_float(u.z << 16);
  f[5] = __uint_as_float(u.z & 0xffff0000u);
  f[6] = __uint_as_float(u.w << 16);
  f[7] = __uint_as_float(u.w & 0xffff0000u);
}

__global__ __launch_bounds__(256, 4) void fused_attn_kernel(
    const float* __restrict__ q, const unsigned short* __restrict__ kv,
    const int* __restrict__ offsets, const int* __restrict__ csr_src,
    int* __restrict__ ticket, float* __restrict__ out, int L) {
  int lane = threadIdx.x & 63;
  const int ntask = L * BB;

  for (;;) {
    int task;
    if (lane == 0) task = atomicAdd(ticket, 1);
    task = __shfl(task, 0);
    if (task >= ntask) return;

    int d = task >> 1;
    int b = task & 1;
    int beg = offsets[d];
    int end = offsets[d + 1];

    const float4* qrow = (const float4*)(q + ((size_t)b * L + d) * ROW);
    float4 q0 = qrow[lane * 2 + 0];
    float4 q1 = qrow[lane * 2 + 1];

    float m = -INFINITY;
    float l_run = 0.0f;
    float acc[8];
#pragma unroll
    for (int i = 0; i < 8; ++i) acc[i] = 0.0f;

    const uint4* kv_base = (const uint4*)(kv + (size_t)b * L * KVROW);

    int t = beg;
    // ---- main loop: full chunks, no conditionals (loads issue back-to-back) ----
    for (; t + CHUNK <= end; t += CHUNK) {
      int srcs[CHUNK];
#pragma unroll
      for (int i = 0; i < CHUNK; ++i) srcs[i] = csr_src[t + i];
      uint4 kk[CHUNK], vv[CHUNK];
#pragma unroll
      for (int i = 0; i < CHUNK; ++i) {
        const uint4* row = kv_base + (size_t)srcs[i] * (KVROW / 8);
        kk[i] = row[lane];
        vv[i] = row[64 + lane];
      }
      float qk[CHUNK];
      float cmax = -INFINITY;
#pragma unroll
      for (int i = 0; i < CHUNK; ++i) {
        float kf[8];
        bf8_unpack(kk[i], kf);
        float p = q0.x * kf[0] + q0.y * kf[1] + q0.z * kf[2] + q0.w * kf[3] +
                  q1.x * kf[4] + q1.y * kf[5] + q1.z * kf[6] + q1.w * kf[7];
        p += __shfl_xor(p, 1);
        p += __shfl_xor(p, 2);
        p += __shfl_xor(p, 4);
        p *= 0.125f;  // softmax_temp = 1/sqrt(64)
        qk[i] = p;
        cmax = fmaxf(cmax, p);
      }
      float mnew = fmaxf(m, cmax);
      float scale = __expf(m - mnew);
      l_run *= scale;
#pragma unroll
      for (int i = 0; i < 8; ++i) acc[i] *= scale;
      m = mnew;
#pragma unroll
      for (int i = 0; i < CHUNK; ++i) {
        float a = __expf(qk[i] - m);
        l_run += a;
        float vf[8];
        bf8_unpack(vv[i], vf);
#pragma unroll
        for (int j = 0; j < 8; ++j) acc[j] += a * vf[j];
      }
    }
    // ---- tail chunk (< CHUNK edges) ----
    int cnt = end - t;
    if (cnt > 0) {
      uint4 kk[CHUNK], vv[CHUNK];
      int srcs[CHUNK];
#pragma unroll
      for (int i = 0; i < CHUNK; ++i) {
        if (i < cnt) {
          srcs[i] = csr_src[t + i];
          const uint4* row = kv_base + (size_t)srcs[i] * (KVROW / 8);
          kk[i] = row[lane];
          vv[i] = row[64 + lane];
        }
      }
      float qk[CHUNK];
      float cmax = -INFINITY;
#pragma unroll
      for (int i = 0; i < CHUNK; ++i) {
        qk[i] = -INFINITY;
        if (i < cnt) {
          float kf[8];
          bf8_unpack(kk[i], kf);
          float p = q0.x * kf[0] + q0.y * kf[1] + q0.z * kf[2] + q0.w * kf[3] +
                    q1.x * kf[4] + q1.y * kf[5] + q1.z * kf[6] + q1.w * kf[7];
          p += __shfl_xor(p, 1);
          p += __shfl_xor(p, 2);
          p += __shfl_xor(p, 4);
          p *= 0.125f;
          qk[i] = p;
          cmax = fmaxf(cmax, p);
        }
      }
      float mnew = fmaxf(m, cmax);
      float scale = __expf(m - mnew);
      l_run *= scale;
#pragma unroll
      for (int i = 0; i < 8; ++i) acc[i] *= scale;
      m = mnew;
#pragma unroll
      for (int i = 0; i < CHUNK; ++i) {
        if (i < cnt) {
          float a = __expf(qk[i] - m);
          l_run += a;
          float vf[8];
          bf8_unpack(vv[i], vf);
#pragma unroll
          for (int j = 0; j < 8; ++j) acc[j] += a * vf[j];
        }
      }
    }

    float r = 1.0f / (l_run + 1e-16f);  // empty segment: acc=0 -> out=0
    float4* orow = (float4*)(out + ((size_t)b * L + d) * ROW);
    orow[lane * 2 + 0] = make_float4(acc[0] * r, acc[1] * r, acc[2] * r, acc[3] * r);
    orow[lane * 2 + 1] = make_float4(acc[4] * r, acc[5] * r, acc[6] * r, acc[7] * r);
  }
}

extern "C" void kernel_launch(void* const* d_in, const int* in_sizes, int n_in,
                              void* d_out, int out_size, void* d_ws, size_t ws_size,
                              hipStream_t stream) {
  const float* q = (const float*)d_in[0];
  const float* k = (const float*)d_in[1];
  const float* v = (const float*)d_in[2];
  const int* adj = (const int*)d_in[3];

  const int NE = in_sizes[3] / 2;
  const int L = in_sizes[0] / (BB * HH * EE);
  const int* dst = adj;
  const int* src = adj + NE;
  const int nelem = BB * L * HH * EE;

  // workspace layout
  char* ws = (char*)d_ws;
  size_t off = 0;
  unsigned short* kvbf = (unsigned short*)(ws + off); off += (size_t)nelem * 2 * 2;  // 41 MB
  int* counts = (int*)(ws + off);   off += (size_t)L * 4;   // doubles as fill cursor
  int* ticket = (int*)(ws + off);   off += 4;
  int* offsets = (int*)(ws + off);  off += (size_t)(L + 1) * 4;
  int* csr_src = (int*)(ws + off);  off += (size_t)NE * 4;

  // zero counts + ticket in one memset
  hipMemsetAsync(counts, 0, (size_t)(L + 1) * 4, stream);

  int n4 = nelem / 4;
  convert_hist_kernel<<<(n4 + 255) / 256, 256, 0, stream>>>(
      k, v, kvbf, dst, counts, n4, NE);

  scan_kernel<<<1, 1024, 0, stream>>>(counts, counts, offsets, L);

  fill_csr_kernel<<<(NE + 255) / 256, 256, 0, stream>>>(
      dst, src, offsets, counts, csr_src, NE);

  // persistent fused attention: enough blocks to fill the device at 4 blocks/CU
  int nblocks = 256 * 5;  // slight oversubscription; extra blocks exit on first ticket
  fused_attn_kernel<<<nblocks, 256, 0, stream>>>(
      q, kvbf, offsets, csr_src, ticket, (float*)d_out, L);
}

// Round 6
// 295.212 us; speedup vs baseline: 1.6503x; 1.6503x over previous
//
#include <hip/hip_runtime.h>

// Problem constants (from reference setup_inputs): B=2, L=10000, H=8, E=64, NE=160000
#define BB 2
#define HH 8
#define EE 64
#define ROW (HH * EE)        // 512 elements per (b, node) row
#define KVROW (2 * ROW)      // interleaved [k|v] row: 1024 bf16 = 2 KB
#define CHUNK 8

// ---------- fp32 -> bf16 (RNE) ----------
__device__ inline unsigned short f2bf(float f) {
  unsigned int u = __float_as_uint(f);
  u = (u + 0x7fffu + ((u >> 16) & 1u)) >> 16;
  return (unsigned short)u;
}

// convert k,v into interleaved bf16 layout kv[b*L+node] = [k(512) | v(512)];
// threads [0, NE) also histogram dst into counts.
__global__ __launch_bounds__(256) void convert_hist_kernel(
    const float* __restrict__ k, const float* __restrict__ v,
    unsigned short* __restrict__ kv,
    const int* __restrict__ dst, int* __restrict__ counts,
    int n4, int NE) {
  int i = blockIdx.x * blockDim.x + threadIdx.x;
  if (i < n4) {
    float4 kf = ((const float4*)k)[i];
    float4 vf = ((const float4*)v)[i];
    int row = i >> 7;          // 128 float4 per 512-elem row
    int p4 = i & 127;
    ushort4* kvrow = (ushort4*)(kv + (size_t)row * KVROW);
    kvrow[p4]       = make_ushort4(f2bf(kf.x), f2bf(kf.y), f2bf(kf.z), f2bf(kf.w));
    kvrow[128 + p4] = make_ushort4(f2bf(vf.x), f2bf(vf.y), f2bf(vf.z), f2bf(vf.w));
  }
  if (i < NE) {
    atomicAdd(&counts[dst[i]], 1);
  }
}

// single-block scan: counts -> offsets[0..L]; zero counts (reused as fill cursor)
__global__ __launch_bounds__(1024) void scan_kernel(
    const int* __restrict__ counts_in, int* __restrict__ counts_mut,
    int* __restrict__ offsets, int L) {
  __shared__ int sums[1024];
  int tid = threadIdx.x;
  int chunk = (L + 1023) / 1024;
  int beg = tid * chunk;
  int end = min(beg + chunk, L);
  int s = 0;
  for (int i = beg; i < end; ++i) s += counts_in[i];
  sums[tid] = s;
  __syncthreads();
  for (int off = 1; off < 1024; off <<= 1) {
    int val = 0;
    if (tid >= off) val = sums[tid - off];
    __syncthreads();
    if (tid >= off) sums[tid] += val;
    __syncthreads();
  }
  int run = (tid > 0) ? sums[tid - 1] : 0;
  for (int i = beg; i < end; ++i) {
    offsets[i] = run;
    run += counts_in[i];
    counts_mut[i] = 0;
  }
  if (tid == 1023) offsets[L] = run;
}

__global__ __launch_bounds__(256) void fill_csr_kernel(
    const int* __restrict__ dst, const int* __restrict__ src,
    const int* __restrict__ offsets, int* __restrict__ cursor,
    int* __restrict__ csr_src, int NE) {
  int e = blockIdx.x * blockDim.x + threadIdx.x;
  if (e >= NE) return;
  int d = dst[e];
  int pos = atomicAdd(&cursor[d], 1);
  csr_src[offsets[d] + pos] = src[e];
}

// ---------- fused flash-style kernel: grid-stride persistent waves ----------
__device__ inline void bf8_unpack(uint4 u, float* f) {
  f[0] = __uint_as_float(u.x << 16);
  f[1] = __uint_as_float(u.x & 0xffff0000u);
  f[2] = __uint_as_float(u.y << 16);
  f[3] = __uint_as_float(u.y & 0xffff0000u);
  f[4] = __uint_as_float(u.z << 16);
  f[5] = __uint_as_float(u.z & 0xffff0000u);
  f[6] = __uint_as_float(u.w << 16);
  f[7] = __uint_as_float(u.w & 0xffff0000u);
}

// launch_bounds(256,3): VGPR cap ~168 — enough for 16 in-flight uint4 chunk
// buffers (~64 VGPR) + state without spilling (R5's (256,4)=128 cap spilled:
// WRITE_SIZE 40->213 MB). 3 blocks/CU = 12 waves/CU.
__global__ __launch_bounds__(256, 3) void fused_attn_kernel(
    const float* __restrict__ q, const unsigned short* __restrict__ kv,
    const int* __restrict__ offsets, const int* __restrict__ csr_src,
    float* __restrict__ out, int L) {
  int lane = threadIdx.x & 63;
  int gwid = blockIdx.x * (blockDim.x >> 6) + (threadIdx.x >> 6);
  int nw = gridDim.x * (blockDim.x >> 6);
  const int ntask = L * BB;

  for (int task = gwid; task < ntask; task += nw) {
    int d = task >> 1;
    int b = task & 1;
    int beg = offsets[d];
    int end = offsets[d + 1];

    const float4* qrow = (const float4*)(q + ((size_t)b * L + d) * ROW);
    float4 q0 = qrow[lane * 2 + 0];
    float4 q1 = qrow[lane * 2 + 1];

    float m = -INFINITY;
    float l_run = 0.0f;
    float acc[8];
#pragma unroll
    for (int i = 0; i < 8; ++i) acc[i] = 0.0f;

    const uint4* kv_base = (const uint4*)(kv + (size_t)b * L * KVROW);

    int t = beg;
    // ---- main loop: full chunks, no conditionals; 16 gathers in flight ----
    for (; t + CHUNK <= end; t += CHUNK) {
      int srcs[CHUNK];
#pragma unroll
      for (int i = 0; i < CHUNK; ++i) srcs[i] = csr_src[t + i];
      uint4 kk[CHUNK], vv[CHUNK];
#pragma unroll
      for (int i = 0; i < CHUNK; ++i) {
        const uint4* row = kv_base + (size_t)srcs[i] * (KVROW / 8);
        kk[i] = row[lane];
        vv[i] = row[64 + lane];
      }
      float qk[CHUNK];
      float cmax = -INFINITY;
#pragma unroll
      for (int i = 0; i < CHUNK; ++i) {
        float kf[8];
        bf8_unpack(kk[i], kf);
        float p = q0.x * kf[0] + q0.y * kf[1] + q0.z * kf[2] + q0.w * kf[3] +
                  q1.x * kf[4] + q1.y * kf[5] + q1.z * kf[6] + q1.w * kf[7];
        p += __shfl_xor(p, 1);
        p += __shfl_xor(p, 2);
        p += __shfl_xor(p, 4);
        p *= 0.125f;  // softmax_temp = 1/sqrt(64)
        qk[i] = p;
        cmax = fmaxf(cmax, p);
      }
      float mnew = fmaxf(m, cmax);
      float scale = __expf(m - mnew);
      l_run *= scale;
#pragma unroll
      for (int i = 0; i < 8; ++i) acc[i] *= scale;
      m = mnew;
#pragma unroll
      for (int i = 0; i < CHUNK; ++i) {
        float a = __expf(qk[i] - m);
        l_run += a;
        float vf[8];
        bf8_unpack(vv[i], vf);
#pragma unroll
        for (int j = 0; j < 8; ++j) acc[j] += a * vf[j];
      }
    }
    // ---- tail chunk (< CHUNK edges) ----
    int cnt = end - t;
    if (cnt > 0) {
      uint4 kk[CHUNK], vv[CHUNK];
#pragma unroll
      for (int i = 0; i < CHUNK; ++i) {
        if (i < cnt) {
          int s = csr_src[t + i];
          const uint4* row = kv_base + (size_t)s * (KVROW / 8);
          kk[i] = row[lane];
          vv[i] = row[64 + lane];
        }
      }
      float qk[CHUNK];
      float cmax = -INFINITY;
#pragma unroll
      for (int i = 0; i < CHUNK; ++i) {
        qk[i] = -INFINITY;
        if (i < cnt) {
          float kf[8];
          bf8_unpack(kk[i], kf);
          float p = q0.x * kf[0] + q0.y * kf[1] + q0.z * kf[2] + q0.w * kf[3] +
                    q1.x * kf[4] + q1.y * kf[5] + q1.z * kf[6] + q1.w * kf[7];
          p += __shfl_xor(p, 1);
          p += __shfl_xor(p, 2);
          p += __shfl_xor(p, 4);
          p *= 0.125f;
          qk[i] = p;
          cmax = fmaxf(cmax, p);
        }
      }
      float mnew = fmaxf(m, cmax);
      float scale = __expf(m - mnew);
      l_run *= scale;
#pragma unroll
      for (int i = 0; i < 8; ++i) acc[i] *= scale;
      m = mnew;
#pragma unroll
      for (int i = 0; i < CHUNK; ++i) {
        if (i < cnt) {
          float a = __expf(qk[i] - m);
          l_run += a;
          float vf[8];
          bf8_unpack(vv[i], vf);
#pragma unroll
          for (int j = 0; j < 8; ++j) acc[j] += a * vf[j];
        }
      }
    }

    float r = 1.0f / (l_run + 1e-16f);  // empty segment: acc=0 -> out=0
    float4* orow = (float4*)(out + ((size_t)b * L + d) * ROW);
    orow[lane * 2 + 0] = make_float4(acc[0] * r, acc[1] * r, acc[2] * r, acc[3] * r);
    orow[lane * 2 + 1] = make_float4(acc[4] * r, acc[5] * r, acc[6] * r, acc[7] * r);
  }
}

extern "C" void kernel_launch(void* const* d_in, const int* in_sizes, int n_in,
                              void* d_out, int out_size, void* d_ws, size_t ws_size,
                              hipStream_t stream) {
  const float* q = (const float*)d_in[0];
  const float* k = (const float*)d_in[1];
  const float* v = (const float*)d_in[2];
  const int* adj = (const int*)d_in[3];

  const int NE = in_sizes[3] / 2;
  const int L = in_sizes[0] / (BB * HH * EE);
  const int* dst = adj;
  const int* src = adj + NE;
  const int nelem = BB * L * HH * EE;

  // workspace layout
  char* ws = (char*)d_ws;
  size_t off = 0;
  unsigned short* kvbf = (unsigned short*)(ws + off); off += (size_t)nelem * 2 * 2;  // 41 MB
  int* counts = (int*)(ws + off);   off += (size_t)L * 4;   // doubles as fill cursor
  int* offsets = (int*)(ws + off);  off += (size_t)(L + 1) * 4;
  int* csr_src = (int*)(ws + off);  off += (size_t)NE * 4;

  hipMemsetAsync(counts, 0, (size_t)L * 4, stream);

  int n4 = nelem / 4;
  convert_hist_kernel<<<(n4 + 255) / 256, 256, 0, stream>>>(
      k, v, kvbf, dst, counts, n4, NE);

  scan_kernel<<<1, 1024, 0, stream>>>(counts, counts, offsets, L);

  fill_csr_kernel<<<(NE + 255) / 256, 256, 0, stream>>>(
      dst, src, offsets, counts, csr_src, NE);

  // grid-stride persistent: 3 blocks/CU x 256 CUs
  fused_attn_kernel<<<256 * 3, 256, 0, stream>>>(
      q, kvbf, offsets, csr_src, (float*)d_out, L);
}